// Round 4
// baseline (310.072 us; speedup 1.0000x reference)
//
#include <hip/hip_runtime.h>

#define N_NODES 10000
#define N_EDGES 640000
#define F_IN 128
#define H1 64
#define H2 32
#define N_CLASSES 16

// ---------- degree count (int4-vectorized edge reads) ----------
__global__ void k_deg(const int* __restrict__ dst, int* __restrict__ degInt) {
    int i = blockIdx.x * blockDim.x + threadIdx.x;
    if (i < N_EDGES / 4) {
        int4 d = ((const int4*)dst)[i];
        atomicAdd(&degInt[d.x], 1);
        atomicAdd(&degInt[d.y], 1);
        atomicAdd(&degInt[d.z], 1);
        atomicAdd(&degInt[d.w], 1);
    }
}

// ---------- one-block scan: rowStart (exclusive) + dinv ----------
__global__ void __launch_bounds__(1024) k_scan(const int* __restrict__ degInt,
                                               float* __restrict__ dinv,
                                               int* __restrict__ rowStart) {
    __shared__ int part[1024];
    const int CH = 10;  // 1024 * 10 = 10240 >= N_NODES
    int t = threadIdx.x;
    int base = t * CH;
    int deg[CH];
    int s = 0;
    for (int i = 0; i < CH; ++i) {
        int idx = base + i;
        deg[i] = (idx < N_NODES) ? degInt[idx] : 0;
        s += deg[i];
    }
    part[t] = s;
    __syncthreads();
    // Hillis-Steele inclusive scan over 1024 partials (10 steps)
    for (int off = 1; off < 1024; off <<= 1) {
        int v = (t >= off) ? part[t - off] : 0;
        __syncthreads();
        part[t] += v;
        __syncthreads();
    }
    int ex = part[t] - s;  // exclusive prefix for this chunk
    for (int i = 0; i < CH; ++i) {
        int idx = base + i;
        if (idx < N_NODES) {
            rowStart[idx] = ex;
            dinv[idx]     = rsqrtf((float)deg[i] + 1.0f);
            ex += deg[i];
        }
    }
    if (t == 1023) rowStart[N_NODES] = part[1023];
}

// ---------- bucketed counting-sort fill ----------
// 125 blocks x 80 nodes. Each block streams all of dst (int4), keeps edges in
// its node range, takes position from an LDS cursor, writes src into its own
// contiguous slice of srcSorted. No global atomics; dense line-filling writes.
#define FILL_BLOCKS 125
#define NODES_PER_BLK 80
__global__ void __launch_bounds__(1024) k_fill_bucket(const int* __restrict__ src,
                                                      const int* __restrict__ dst,
                                                      const int* __restrict__ rowStart,
                                                      int* __restrict__ srcSorted) {
    __shared__ int lcur[NODES_PER_BLK];
    int t = threadIdx.x;
    int base = blockIdx.x * NODES_PER_BLK;
    if (t < NODES_PER_BLK) lcur[t] = rowStart[base + t];
    __syncthreads();
    const int4* dst4 = (const int4*)dst;
    const int nv = N_EDGES / 4;  // 160000
    for (int i = t; i < nv; i += 1024) {
        int4 d4 = dst4[i];
        int e = i * 4;
        int d;
        d = d4.x - base;
        if ((unsigned)d < NODES_PER_BLK) { int p = atomicAdd(&lcur[d], 1); srcSorted[p] = src[e]; }
        d = d4.y - base;
        if ((unsigned)d < NODES_PER_BLK) { int p = atomicAdd(&lcur[d], 1); srcSorted[p] = src[e + 1]; }
        d = d4.z - base;
        if ((unsigned)d < NODES_PER_BLK) { int p = atomicAdd(&lcur[d], 1); srcSorted[p] = src[e + 2]; }
        d = d4.w - base;
        if ((unsigned)d < NODES_PER_BLK) { int p = atomicAdd(&lcur[d], 1); srcSorted[p] = src[e + 3]; }
    }
}

// ---------- layer1 GEMM: h1hat = (x @ W1) * dinv ----------
// block = 256 threads = 4 nodes x 64 outputs
__global__ void k_gemm1(const float* __restrict__ x,
                        const float* __restrict__ W1,
                        const float* __restrict__ dinv,
                        float* __restrict__ h1hat) {
    __shared__ __align__(16) float xs[4][F_IN];
    int t = threadIdx.x;
    int node0 = blockIdx.x * 4;
    const float4* x4 = (const float4*)x;
    if (t < 128) {
        int r = t >> 5, c4 = t & 31;
        int v = node0 + r;
        float4 val = (v < N_NODES) ? x4[v * (F_IN / 4) + c4]
                                   : make_float4(0.f, 0.f, 0.f, 0.f);
        ((float4*)xs[r])[c4] = val;
    }
    __syncthreads();
    int r = t >> 6;
    int j = t & 63;
    int v = node0 + r;
    if (v >= N_NODES) return;
    float acc = 0.f;
#pragma unroll 8
    for (int k = 0; k < F_IN; ++k)
        acc += xs[r][k] * W1[k * H1 + j];
    h1hat[v * H1 + j] = acc * dinv[v];
}

// ---------- gather layer1 (CSR) + ReLU + GEMM2 + dinv-scale ----------
// block = 256 = 4 waves; wave w owns node v, lane j = feature of h1
__global__ void k_gather1_gemm2(const float* __restrict__ h1hat,
                                const int* __restrict__ rowStart,
                                const int* __restrict__ srcSorted,
                                const float* __restrict__ dinv,
                                const float* __restrict__ b1,
                                const float* __restrict__ W2,
                                float* __restrict__ h2hat) {
    __shared__ float h1s[4][H1];
    int t = threadIdx.x;
    int w = t >> 6, j = t & 63;
    int v = blockIdx.x * 4 + w;
    float dv_ = 0.f;
    if (v < N_NODES) {
        dv_ = dinv[v];
        int rs = rowStart[v], re = rowStart[v + 1];
        float sum = h1hat[v * H1 + j];  // self-loop term
        float s0 = 0.f, s1 = 0.f, s2 = 0.f, s3 = 0.f;
        int e = rs;
        for (; e + 4 <= re; e += 4) {
            int a0 = srcSorted[e], a1 = srcSorted[e + 1];
            int a2 = srcSorted[e + 2], a3 = srcSorted[e + 3];
            s0 += h1hat[a0 * H1 + j];
            s1 += h1hat[a1 * H1 + j];
            s2 += h1hat[a2 * H1 + j];
            s3 += h1hat[a3 * H1 + j];
        }
        for (; e < re; ++e) sum += h1hat[srcSorted[e] * H1 + j];
        sum += (s0 + s1) + (s2 + s3);
        h1s[w][j] = fmaxf(dv_ * sum + b1[j], 0.f);  // h1 (post-ReLU)
    }
    __syncthreads();
    if (v < N_NODES && j < H2) {
        float acc = 0.f;
#pragma unroll
        for (int kk = 0; kk < H1; ++kk)
            acc += h1s[w][kk] * W2[kk * H2 + j];
        h2hat[v * H2 + j] = acc * dv_;  // pre-scaled for layer-2 aggregation
    }
}

// ---------- gather layer2 (CSR) + ReLU + block mean reduce ----------
// block = 256 = 8 nodes x 32 features (half-wave per node)
__global__ void k_gather2_mean(const float* __restrict__ h2hat,
                               const int* __restrict__ rowStart,
                               const int* __restrict__ srcSorted,
                               const float* __restrict__ dinv,
                               const float* __restrict__ b2,
                               float* __restrict__ g) {
    __shared__ float red[256];
    int t = threadIdx.x;
    int slot = t >> 5;  // 0..7
    int j = t & 31;
    int v = blockIdx.x * 8 + slot;
    float val = 0.f;
    if (v < N_NODES) {
        float dv_ = dinv[v];
        int rs = rowStart[v], re = rowStart[v + 1];
        float sum = h2hat[v * H2 + j];  // self-loop term
        float s0 = 0.f, s1 = 0.f;
        int e = rs;
        for (; e + 2 <= re; e += 2) {
            int a0 = srcSorted[e], a1 = srcSorted[e + 1];
            s0 += h2hat[a0 * H2 + j];
            s1 += h2hat[a1 * H2 + j];
        }
        for (; e < re; ++e) sum += h2hat[srcSorted[e] * H2 + j];
        sum += s0 + s1;
        val = fmaxf(dv_ * sum + b2[j], 0.f);
    }
    red[t] = val;
    __syncthreads();
    if (t < 32) {
        float s = 0.f;
#pragma unroll
        for (int r = 0; r < 8; ++r) s += red[r * 32 + t];
        atomicAdd(&g[t], s);
    }
}

// ---------- final FC ----------
__global__ void k_out(const float* __restrict__ g,
                      const float* __restrict__ Wfc,
                      const float* __restrict__ bfc,
                      float* __restrict__ out) {
    int c = threadIdx.x;
    if (c < N_CLASSES) {
        float acc = 0.f;
#pragma unroll
        for (int j = 0; j < H2; ++j)
            acc += g[j] * Wfc[j * N_CLASSES + c];
        float invN = 1.0f / (float)N_NODES;
        out[c] = acc * invN + bfc[c];
    }
}

extern "C" void kernel_launch(void* const* d_in, const int* in_sizes, int n_in,
                              void* d_out, int out_size, void* d_ws, size_t ws_size,
                              hipStream_t stream) {
    const float* x   = (const float*)d_in[0];
    const float* W1  = (const float*)d_in[1];
    const float* b1  = (const float*)d_in[2];
    const float* W2  = (const float*)d_in[3];
    const float* b2  = (const float*)d_in[4];
    const float* Wfc = (const float*)d_in[5];
    const float* bfc = (const float*)d_in[6];
    const int* edge = (const int*)d_in[7];
    const int* srcI = edge;              // edge_index[0]
    const int* dstI = edge + N_EDGES;    // edge_index[1]
    float* out = (float*)d_out;

    // workspace layout
    char* ws = (char*)d_ws;
    int*   degInt    = (int*)  (ws + 0);        // 10000 ints
    float* dinv      = (float*)(ws + 40960);    // 10000 f
    int*   rowStart  = (int*)  (ws + 81920);    // 10001 ints
    int*   srcSorted = (int*)  (ws + 163840);   // 640000 ints
    float* h1hat     = (float*)(ws + 163840 + 2560000);            // 640000 f
    float* h2hat     = (float*)(ws + 163840 + 2 * 2560000);        // 320000 f
    float* g         = (float*)(ws + 163840 + 2 * 2560000 + 1280000); // 32 f

    hipMemsetAsync(degInt, 0, N_NODES * sizeof(int), stream);
    hipMemsetAsync(g, 0, H2 * sizeof(float), stream);

    k_deg<<<(N_EDGES / 4 + 255) / 256, 256, 0, stream>>>(dstI, degInt);
    k_scan<<<1, 1024, 0, stream>>>(degInt, dinv, rowStart);
    k_fill_bucket<<<FILL_BLOCKS, 1024, 0, stream>>>(srcI, dstI, rowStart, srcSorted);
    k_gemm1<<<(N_NODES + 3) / 4, 256, 0, stream>>>(x, W1, dinv, h1hat);
    k_gather1_gemm2<<<(N_NODES + 3) / 4, 256, 0, stream>>>(h1hat, rowStart, srcSorted,
                                                           dinv, b1, W2, h2hat);
    k_gather2_mean<<<(N_NODES + 7) / 8, 256, 0, stream>>>(h2hat, rowStart, srcSorted,
                                                          dinv, b2, g);
    k_out<<<1, 64, 0, stream>>>(g, Wfc, bfc, out);
}

// Round 5
// 171.391 us; speedup vs baseline: 1.8092x; 1.8092x over previous
//
#include <hip/hip_runtime.h>

#define N_NODES 10000
#define N_EDGES 640000
#define F_IN 128
#define H1 64
#define H2 32
#define N_CLASSES 16

#define NB 128        // radix buckets
#define NPB 79        // nodes per bucket (79*128 = 10112 >= 10000)
#define STAGE_C 64    // per-bucket LDS staging capacity (mean 16/blk, +12 sigma)
#define SLOT 6144     // per-bucket partBuf capacity (mean ~5056, +15 sigma)

// ---------- pass 1: partition edges into 128 dst-range buckets ----------
// pack: src (14 bits, <10000) | local_dst (7 bits, <79) << 14
__global__ void __launch_bounds__(256) k_part(const int* __restrict__ src,
                                              const int* __restrict__ dst,
                                              int* __restrict__ bucketCursor,
                                              int* __restrict__ partBuf) {
    __shared__ int cnt[NB];
    __shared__ int gbase[NB];
    __shared__ int stage[NB * STAGE_C];
    int t = threadIdx.x;
    if (t < NB) cnt[t] = 0;
    __syncthreads();
    const int4* src4 = (const int4*)src;
    const int4* dst4 = (const int4*)dst;
#pragma unroll
    for (int k = 0; k < 2; ++k) {
        int i4 = blockIdx.x * 512 + k * 256 + t;
        if (i4 < N_EDGES / 4) {
            int4 s = src4[i4];
            int4 d = dst4[i4];
            int b, l, p;
            b = d.x / NPB; l = d.x - b * NPB; p = atomicAdd(&cnt[b], 1); stage[b * STAGE_C + p] = s.x | (l << 14);
            b = d.y / NPB; l = d.y - b * NPB; p = atomicAdd(&cnt[b], 1); stage[b * STAGE_C + p] = s.y | (l << 14);
            b = d.z / NPB; l = d.z - b * NPB; p = atomicAdd(&cnt[b], 1); stage[b * STAGE_C + p] = s.z | (l << 14);
            b = d.w / NPB; l = d.w - b * NPB; p = atomicAdd(&cnt[b], 1); stage[b * STAGE_C + p] = s.w | (l << 14);
        }
    }
    __syncthreads();
    if (t < NB) gbase[t] = atomicAdd(&bucketCursor[t], cnt[t]);
    __syncthreads();
    for (int i = t; i < NB * STAGE_C; i += 256) {
        int b = i >> 6;            // / STAGE_C
        int k = i & (STAGE_C - 1);
        if (k < cnt[b]) partBuf[b * SLOT + gbase[b] + k] = stage[i];
    }
}

// ---------- pass 2: per-bucket counting sort -> srcSorted, rowStart, dinv ----------
__global__ void __launch_bounds__(256) k_bsort(const int* __restrict__ bucketCursor,
                                               const int* __restrict__ partBuf,
                                               int* __restrict__ srcSorted,
                                               int* __restrict__ rowStart,
                                               float* __restrict__ dinv) {
    __shared__ int sc[NB];
    __shared__ int ldeg[NPB];
    __shared__ int lpre[NPB];
    __shared__ int cur[NPB];
    int t = threadIdx.x;
    int b = blockIdx.x;
    if (b == 0 && t == 0) rowStart[N_NODES] = N_EDGES;
    // redundant per-block scan of all 128 bucket totals
    if (t < NB) sc[t] = bucketCursor[t];
    __syncthreads();
    for (int off = 1; off < NB; off <<= 1) {
        int v = (t >= off && t < NB) ? sc[t - off] : 0;
        __syncthreads();
        if (t < NB) sc[t] += v;
        __syncthreads();
    }
    int cnt = bucketCursor[b];
    int base = sc[b] - cnt;  // exclusive prefix
    int nodeBase = b * NPB;
    int nNodes = N_NODES - nodeBase;
    if (nNodes <= 0) return;  // bucket 127 is empty
    if (nNodes > NPB) nNodes = NPB;
    if (t < NPB) ldeg[t] = 0;
    __syncthreads();
    // count local degrees
    for (int i = t; i < cnt; i += 256) {
        int p = partBuf[b * SLOT + i];
        atomicAdd(&ldeg[p >> 14], 1);
    }
    __syncthreads();
    if (t == 0) {
        int run = 0;
        for (int i = 0; i < nNodes; ++i) { lpre[i] = run; run += ldeg[i]; }
    }
    __syncthreads();
    if (t < nNodes) {
        int v = nodeBase + t;
        rowStart[v] = base + lpre[t];
        cur[t] = lpre[t];
        dinv[v] = rsqrtf((float)ldeg[t] + 1.0f);
    }
    __syncthreads();
    // place
    for (int i = t; i < cnt; i += 256) {
        int p = partBuf[b * SLOT + i];
        int pos = atomicAdd(&cur[p >> 14], 1);
        srcSorted[base + pos] = p & 16383;
    }
}

// ---------- layer1 GEMM: h1hat = (x @ W1) * dinv ----------
// block = 256 threads = 4 nodes x 64 outputs
__global__ void k_gemm1(const float* __restrict__ x,
                        const float* __restrict__ W1,
                        const float* __restrict__ dinv,
                        float* __restrict__ h1hat) {
    __shared__ __align__(16) float xs[4][F_IN];
    int t = threadIdx.x;
    int node0 = blockIdx.x * 4;
    const float4* x4 = (const float4*)x;
    if (t < 128) {
        int r = t >> 5, c4 = t & 31;
        int v = node0 + r;
        float4 val = (v < N_NODES) ? x4[v * (F_IN / 4) + c4]
                                   : make_float4(0.f, 0.f, 0.f, 0.f);
        ((float4*)xs[r])[c4] = val;
    }
    __syncthreads();
    int r = t >> 6;
    int j = t & 63;
    int v = node0 + r;
    if (v >= N_NODES) return;
    float acc = 0.f;
#pragma unroll 8
    for (int k = 0; k < F_IN; ++k)
        acc += xs[r][k] * W1[k * H1 + j];
    h1hat[v * H1 + j] = acc * dinv[v];
}

// ---------- gather layer1 (CSR) + ReLU + GEMM2 + dinv-scale ----------
// block = 256 = 4 waves; wave w owns node v, lane j = feature of h1
__global__ void k_gather1_gemm2(const float* __restrict__ h1hat,
                                const int* __restrict__ rowStart,
                                const int* __restrict__ srcSorted,
                                const float* __restrict__ dinv,
                                const float* __restrict__ b1,
                                const float* __restrict__ W2,
                                float* __restrict__ h2hat) {
    __shared__ float h1s[4][H1];
    int t = threadIdx.x;
    int w = t >> 6, j = t & 63;
    int v = blockIdx.x * 4 + w;
    float dv_ = 0.f;
    if (v < N_NODES) {
        dv_ = dinv[v];
        int rs = rowStart[v], re = rowStart[v + 1];
        float sum = h1hat[v * H1 + j];  // self-loop term
        float s0 = 0.f, s1 = 0.f, s2 = 0.f, s3 = 0.f;
        int e = rs;
        for (; e + 4 <= re; e += 4) {
            int a0 = srcSorted[e], a1 = srcSorted[e + 1];
            int a2 = srcSorted[e + 2], a3 = srcSorted[e + 3];
            s0 += h1hat[a0 * H1 + j];
            s1 += h1hat[a1 * H1 + j];
            s2 += h1hat[a2 * H1 + j];
            s3 += h1hat[a3 * H1 + j];
        }
        for (; e < re; ++e) sum += h1hat[srcSorted[e] * H1 + j];
        sum += (s0 + s1) + (s2 + s3);
        h1s[w][j] = fmaxf(dv_ * sum + b1[j], 0.f);  // h1 (post-ReLU)
    }
    __syncthreads();
    if (v < N_NODES && j < H2) {
        float acc = 0.f;
#pragma unroll
        for (int kk = 0; kk < H1; ++kk)
            acc += h1s[w][kk] * W2[kk * H2 + j];
        h2hat[v * H2 + j] = acc * dv_;  // pre-scaled for layer-2 aggregation
    }
}

// ---------- gather layer2 (CSR) + ReLU + block mean reduce ----------
// block = 256 = 8 nodes x 32 features (half-wave per node)
__global__ void k_gather2_mean(const float* __restrict__ h2hat,
                               const int* __restrict__ rowStart,
                               const int* __restrict__ srcSorted,
                               const float* __restrict__ dinv,
                               const float* __restrict__ b2,
                               float* __restrict__ g) {
    __shared__ float red[256];
    int t = threadIdx.x;
    int slot = t >> 5;  // 0..7
    int j = t & 31;
    int v = blockIdx.x * 8 + slot;
    float val = 0.f;
    if (v < N_NODES) {
        float dv_ = dinv[v];
        int rs = rowStart[v], re = rowStart[v + 1];
        float sum = h2hat[v * H2 + j];  // self-loop term
        float s0 = 0.f, s1 = 0.f;
        int e = rs;
        for (; e + 2 <= re; e += 2) {
            int a0 = srcSorted[e], a1 = srcSorted[e + 1];
            s0 += h2hat[a0 * H2 + j];
            s1 += h2hat[a1 * H2 + j];
        }
        for (; e < re; ++e) sum += h2hat[srcSorted[e] * H2 + j];
        sum += s0 + s1;
        val = fmaxf(dv_ * sum + b2[j], 0.f);
    }
    red[t] = val;
    __syncthreads();
    if (t < 32) {
        float s = 0.f;
#pragma unroll
        for (int r = 0; r < 8; ++r) s += red[r * 32 + t];
        atomicAdd(&g[t], s);
    }
}

// ---------- final FC ----------
__global__ void k_out(const float* __restrict__ g,
                      const float* __restrict__ Wfc,
                      const float* __restrict__ bfc,
                      float* __restrict__ out) {
    int c = threadIdx.x;
    if (c < N_CLASSES) {
        float acc = 0.f;
#pragma unroll
        for (int j = 0; j < H2; ++j)
            acc += g[j] * Wfc[j * N_CLASSES + c];
        float invN = 1.0f / (float)N_NODES;
        out[c] = acc * invN + bfc[c];
    }
}

extern "C" void kernel_launch(void* const* d_in, const int* in_sizes, int n_in,
                              void* d_out, int out_size, void* d_ws, size_t ws_size,
                              hipStream_t stream) {
    const float* x   = (const float*)d_in[0];
    const float* W1  = (const float*)d_in[1];
    const float* b1  = (const float*)d_in[2];
    const float* W2  = (const float*)d_in[3];
    const float* b2  = (const float*)d_in[4];
    const float* Wfc = (const float*)d_in[5];
    const float* bfc = (const float*)d_in[6];
    const int* edge = (const int*)d_in[7];
    const int* srcI = edge;              // edge_index[0]
    const int* dstI = edge + N_EDGES;    // edge_index[1]
    float* out = (float*)d_out;

    // workspace layout (partBuf overlapped with h1hat/h2hat: partBuf is dead
    // after k_bsort, h1hat first written by k_gemm1 — stream order serializes)
    char* ws = (char*)d_ws;
    int*   bucketCursor = (int*)  (ws + 0);        // 128 ints
    float* g            = (float*)(ws + 512);      // 32 f
    float* dinv         = (float*)(ws + 1024);     // 10000 f
    int*   rowStart     = (int*)  (ws + 41984);    // 10001 ints
    int*   srcSorted    = (int*)  (ws + 82944);    // 640000 ints
    int*   partBuf      = (int*)  (ws + 2643968);  // 128*6144 ints (3.15 MB)
    float* h1hat        = (float*)(ws + 2643968);  // 640000 f (overlays partBuf)
    float* h2hat        = (float*)(ws + 5203968);  // 320000 f
    // end = 6483968 bytes (< 7.82 MB used successfully in R3)

    hipMemsetAsync(bucketCursor, 0, 640, stream);  // bucketCursor + g

    k_part<<<(N_EDGES / 4 + 511) / 512, 256, 0, stream>>>(srcI, dstI, bucketCursor, partBuf);
    k_bsort<<<NB, 256, 0, stream>>>(bucketCursor, partBuf, srcSorted, rowStart, dinv);
    k_gemm1<<<(N_NODES + 3) / 4, 256, 0, stream>>>(x, W1, dinv, h1hat);
    k_gather1_gemm2<<<(N_NODES + 3) / 4, 256, 0, stream>>>(h1hat, rowStart, srcSorted,
                                                           dinv, b1, W2, h2hat);
    k_gather2_mean<<<(N_NODES + 7) / 8, 256, 0, stream>>>(h2hat, rowStart, srcSorted,
                                                          dinv, b2, g);
    k_out<<<1, 64, 0, stream>>>(g, Wfc, bfc, out);
}

// Round 6
// 148.475 us; speedup vs baseline: 2.0884x; 1.1543x over previous
//
#include <hip/hip_runtime.h>
#include <hip/hip_bf16.h>

#define N_NODES 10000
#define N_EDGES 640000
#define F_IN 128
#define H1 64
#define H2 32
#define N_CLASSES 16

#define NB 128        // radix buckets
#define NPB 79        // nodes per bucket (79*128 = 10112 >= 10000)
#define STAGE_C 64    // per-bucket LDS staging capacity (mean 16/blk)
#define SLOT 6144     // per-bucket partBuf capacity (mean ~5056)

// ---------- pass 1: partition edges into 128 dst-range buckets ----------
// pack: src (14 bits, <10000) | local_dst (7 bits, <79) << 14
__global__ void __launch_bounds__(256) k_part(const int* __restrict__ src,
                                              const int* __restrict__ dst,
                                              int* __restrict__ bucketCursor,
                                              int* __restrict__ partBuf) {
    __shared__ int cnt[NB];
    __shared__ int gbase[NB];
    __shared__ int stage[NB * STAGE_C];
    int t = threadIdx.x;
    if (t < NB) cnt[t] = 0;
    __syncthreads();
    const int4* src4 = (const int4*)src;
    const int4* dst4 = (const int4*)dst;
#pragma unroll
    for (int k = 0; k < 2; ++k) {
        int i4 = blockIdx.x * 512 + k * 256 + t;
        if (i4 < N_EDGES / 4) {
            int4 s = src4[i4];
            int4 d = dst4[i4];
            int b, l, p;
            b = d.x / NPB; l = d.x - b * NPB; p = atomicAdd(&cnt[b], 1); stage[b * STAGE_C + p] = s.x | (l << 14);
            b = d.y / NPB; l = d.y - b * NPB; p = atomicAdd(&cnt[b], 1); stage[b * STAGE_C + p] = s.y | (l << 14);
            b = d.z / NPB; l = d.z - b * NPB; p = atomicAdd(&cnt[b], 1); stage[b * STAGE_C + p] = s.z | (l << 14);
            b = d.w / NPB; l = d.w - b * NPB; p = atomicAdd(&cnt[b], 1); stage[b * STAGE_C + p] = s.w | (l << 14);
        }
    }
    __syncthreads();
    if (t < NB) gbase[t] = atomicAdd(&bucketCursor[t], cnt[t]);
    __syncthreads();
    for (int i = t; i < NB * STAGE_C; i += 256) {
        int b = i >> 6;            // / STAGE_C
        int k = i & (STAGE_C - 1);
        if (k < cnt[b]) partBuf[b * SLOT + gbase[b] + k] = stage[i];
    }
}

// ---------- pass 2: per-bucket counting sort -> srcSorted, rowStart, dinv ----------
__global__ void __launch_bounds__(512) k_bsort(const int* __restrict__ bucketCursor,
                                               const int* __restrict__ partBuf,
                                               int* __restrict__ srcSorted,
                                               int* __restrict__ rowStart,
                                               float* __restrict__ dinv) {
    __shared__ int sc[NB];
    __shared__ int ldeg[NPB];
    __shared__ int lpre[NPB];
    __shared__ int cur[NPB];
    int t = threadIdx.x;
    int b = blockIdx.x;
    if (b == 0 && t == 0) rowStart[N_NODES] = N_EDGES;
    // redundant per-block scan of all 128 bucket totals
    if (t < NB) sc[t] = bucketCursor[t];
    __syncthreads();
    for (int off = 1; off < NB; off <<= 1) {
        int v = (t >= off && t < NB) ? sc[t - off] : 0;
        __syncthreads();
        if (t < NB) sc[t] += v;
        __syncthreads();
    }
    int cnt = bucketCursor[b];
    int base = sc[b] - cnt;  // exclusive prefix
    int nodeBase = b * NPB;
    int nNodes = N_NODES - nodeBase;
    if (nNodes <= 0) return;  // bucket 127 is empty
    if (nNodes > NPB) nNodes = NPB;
    if (t < NPB) ldeg[t] = 0;
    __syncthreads();
    // count local degrees
    for (int i = t; i < cnt; i += 512) {
        int p = partBuf[b * SLOT + i];
        atomicAdd(&ldeg[p >> 14], 1);
    }
    __syncthreads();
    if (t == 0) {
        int run = 0;
        for (int i = 0; i < nNodes; ++i) { lpre[i] = run; run += ldeg[i]; }
    }
    __syncthreads();
    if (t < nNodes) {
        int v = nodeBase + t;
        rowStart[v] = base + lpre[t];
        cur[t] = lpre[t];
        dinv[v] = rsqrtf((float)ldeg[t] + 1.0f);
    }
    __syncthreads();
    // place
    for (int i = t; i < cnt; i += 512) {
        int p = partBuf[b * SLOT + i];
        int pos = atomicAdd(&cur[p >> 14], 1);
        srcSorted[base + pos] = p & 16383;
    }
}

// ---------- layer1 GEMM: h1b = bf16((x @ W1) * dinv) ----------
// 625 blocks x 256 threads; 16 nodes/block; W1 (32KB) + x tile (8KB) in LDS.
// Thread = output j (t&63) for 4 nodes of wave (t>>6); xs reads are
// wave-uniform broadcasts; w1s[k][j] is 2-way bank aliasing (free).
__global__ void __launch_bounds__(256) k_gemm1(const float* __restrict__ x,
                                               const float* __restrict__ W1,
                                               const float* __restrict__ dinv,
                                               __hip_bfloat16* __restrict__ h1b) {
    __shared__ __align__(16) float w1s[F_IN][H1];  // 32 KB
    __shared__ __align__(16) float xs[16][F_IN];   // 8 KB
    int t = threadIdx.x;
    int node0 = blockIdx.x * 16;  // 625*16 = 10000 exact
    const float4* W14 = (const float4*)W1;
    float4* w1s4 = (float4*)w1s;
#pragma unroll
    for (int i = 0; i < 8; ++i) w1s4[i * 256 + t] = W14[i * 256 + t];
    const float4* x4 = (const float4*)(x + (long)node0 * F_IN);
    float4* xs4 = (float4*)xs;
#pragma unroll
    for (int i = 0; i < 2; ++i) xs4[i * 256 + t] = x4[i * 256 + t];
    __syncthreads();
    int j = t & 63;
    int q = t >> 6;       // wave id 0..3
    int r0 = q * 4;
    float acc0 = 0.f, acc1 = 0.f, acc2 = 0.f, acc3 = 0.f;
#pragma unroll 4
    for (int k = 0; k < F_IN; ++k) {
        float w = w1s[k][j];
        acc0 += xs[r0 + 0][k] * w;
        acc1 += xs[r0 + 1][k] * w;
        acc2 += xs[r0 + 2][k] * w;
        acc3 += xs[r0 + 3][k] * w;
    }
    int v0 = node0 + r0;
    h1b[(v0 + 0) * H1 + j] = __float2bfloat16(acc0 * dinv[v0 + 0]);
    h1b[(v0 + 1) * H1 + j] = __float2bfloat16(acc1 * dinv[v0 + 1]);
    h1b[(v0 + 2) * H1 + j] = __float2bfloat16(acc2 * dinv[v0 + 2]);
    h1b[(v0 + 3) * H1 + j] = __float2bfloat16(acc3 * dinv[v0 + 3]);
}

// ---------- gather layer1 (CSR, bf16) + ReLU + GEMM2 + dinv-scale ----------
// 2500 blocks x 256 = 4 waves; wave w owns node v, lane j = feature of h1
__global__ void __launch_bounds__(256) k_gather1_gemm2(const __hip_bfloat16* __restrict__ h1b,
                                const int* __restrict__ rowStart,
                                const int* __restrict__ srcSorted,
                                const float* __restrict__ dinv,
                                const float* __restrict__ b1,
                                const float* __restrict__ W2,
                                __hip_bfloat16* __restrict__ h2b) {
    __shared__ float h1s[4][H1];
    int t = threadIdx.x;
    int w = t >> 6, j = t & 63;
    int v = blockIdx.x * 4 + w;   // 2500*4 = 10000 exact
    float dv_ = dinv[v];
    int rs = rowStart[v], re = rowStart[v + 1];
    float sum = __bfloat162float(h1b[v * H1 + j]);  // self-loop term
    float s0 = 0.f, s1 = 0.f, s2 = 0.f, s3 = 0.f;
    float s4 = 0.f, s5 = 0.f, s6 = 0.f, s7 = 0.f;
    int e = rs;
    for (; e + 8 <= re; e += 8) {
        int a0 = srcSorted[e], a1 = srcSorted[e + 1];
        int a2 = srcSorted[e + 2], a3 = srcSorted[e + 3];
        int a4 = srcSorted[e + 4], a5 = srcSorted[e + 5];
        int a6 = srcSorted[e + 6], a7 = srcSorted[e + 7];
        s0 += __bfloat162float(h1b[a0 * H1 + j]);
        s1 += __bfloat162float(h1b[a1 * H1 + j]);
        s2 += __bfloat162float(h1b[a2 * H1 + j]);
        s3 += __bfloat162float(h1b[a3 * H1 + j]);
        s4 += __bfloat162float(h1b[a4 * H1 + j]);
        s5 += __bfloat162float(h1b[a5 * H1 + j]);
        s6 += __bfloat162float(h1b[a6 * H1 + j]);
        s7 += __bfloat162float(h1b[a7 * H1 + j]);
    }
    for (; e < re; ++e) sum += __bfloat162float(h1b[srcSorted[e] * H1 + j]);
    sum += ((s0 + s1) + (s2 + s3)) + ((s4 + s5) + (s6 + s7));
    h1s[w][j] = fmaxf(dv_ * sum + b1[j], 0.f);  // h1 (post-ReLU)
    __syncthreads();
    if (j < H2) {
        float acc = 0.f;
#pragma unroll
        for (int kk = 0; kk < H1; ++kk)
            acc += h1s[w][kk] * W2[kk * H2 + j];
        h2b[v * H2 + j] = __float2bfloat16(acc * dv_);  // pre-scaled
    }
}

// ---------- gather layer2 (CSR, bf16) + ReLU + block mean reduce ----------
// 1250 blocks x 256 = 8 nodes x 32 features
__global__ void __launch_bounds__(256) k_gather2_mean(const __hip_bfloat16* __restrict__ h2b,
                               const int* __restrict__ rowStart,
                               const int* __restrict__ srcSorted,
                               const float* __restrict__ dinv,
                               const float* __restrict__ b2,
                               float* __restrict__ g) {
    __shared__ float red[256];
    int t = threadIdx.x;
    int slot = t >> 5;  // 0..7
    int j = t & 31;
    int v = blockIdx.x * 8 + slot;  // 1250*8 = 10000 exact
    float dv_ = dinv[v];
    int rs = rowStart[v], re = rowStart[v + 1];
    float sum = __bfloat162float(h2b[v * H2 + j]);  // self-loop term
    float s0 = 0.f, s1 = 0.f, s2 = 0.f, s3 = 0.f;
    int e = rs;
    for (; e + 4 <= re; e += 4) {
        int a0 = srcSorted[e], a1 = srcSorted[e + 1];
        int a2 = srcSorted[e + 2], a3 = srcSorted[e + 3];
        s0 += __bfloat162float(h2b[a0 * H2 + j]);
        s1 += __bfloat162float(h2b[a1 * H2 + j]);
        s2 += __bfloat162float(h2b[a2 * H2 + j]);
        s3 += __bfloat162float(h2b[a3 * H2 + j]);
    }
    for (; e < re; ++e) sum += __bfloat162float(h2b[srcSorted[e] * H2 + j]);
    sum += (s0 + s1) + (s2 + s3);
    red[t] = fmaxf(dv_ * sum + b2[j], 0.f);
    __syncthreads();
    if (t < 32) {
        float s = 0.f;
#pragma unroll
        for (int r = 0; r < 8; ++r) s += red[r * 32 + t];
        atomicAdd(&g[t], s);
    }
}

// ---------- final FC ----------
__global__ void k_out(const float* __restrict__ g,
                      const float* __restrict__ Wfc,
                      const float* __restrict__ bfc,
                      float* __restrict__ out) {
    int c = threadIdx.x;
    if (c < N_CLASSES) {
        float acc = 0.f;
#pragma unroll
        for (int j = 0; j < H2; ++j)
            acc += g[j] * Wfc[j * N_CLASSES + c];
        float invN = 1.0f / (float)N_NODES;
        out[c] = acc * invN + bfc[c];
    }
}

extern "C" void kernel_launch(void* const* d_in, const int* in_sizes, int n_in,
                              void* d_out, int out_size, void* d_ws, size_t ws_size,
                              hipStream_t stream) {
    const float* x   = (const float*)d_in[0];
    const float* W1  = (const float*)d_in[1];
    const float* b1  = (const float*)d_in[2];
    const float* W2  = (const float*)d_in[3];
    const float* b2  = (const float*)d_in[4];
    const float* Wfc = (const float*)d_in[5];
    const float* bfc = (const float*)d_in[6];
    const int* edge = (const int*)d_in[7];
    const int* srcI = edge;              // edge_index[0]
    const int* dstI = edge + N_EDGES;    // edge_index[1]
    float* out = (float*)d_out;

    // workspace layout. partBuf is dead after k_bsort; h1b/h2b overlay it
    // (first written by k_gemm1 / k_gather1_gemm2, stream-order serialized).
    char* ws = (char*)d_ws;
    int*   bucketCursor = (int*)  (ws + 0);        // 128 ints
    float* g            = (float*)(ws + 512);      // 32 f
    float* dinv         = (float*)(ws + 1024);     // 10000 f
    int*   rowStart     = (int*)  (ws + 41984);    // 10001 ints
    int*   srcSorted    = (int*)  (ws + 82944);    // 640000 ints -> ends 2642944
    int*   partBuf      = (int*)  (ws + 2643968);  // 128*6144 ints -> ends 5789696
    __hip_bfloat16* h1b = (__hip_bfloat16*)(ws + 2643968);  // 640000 bf16 (overlays partBuf)
    __hip_bfloat16* h2b = (__hip_bfloat16*)(ws + 3923968);  // 320000 bf16 (overlays partBuf)

    hipMemsetAsync(bucketCursor, 0, 640, stream);  // bucketCursor + g

    k_part<<<(N_EDGES / 4 + 511) / 512, 256, 0, stream>>>(srcI, dstI, bucketCursor, partBuf);
    k_bsort<<<NB, 512, 0, stream>>>(bucketCursor, partBuf, srcSorted, rowStart, dinv);
    k_gemm1<<<N_NODES / 16, 256, 0, stream>>>(x, W1, dinv, h1b);
    k_gather1_gemm2<<<N_NODES / 4, 256, 0, stream>>>(h1b, rowStart, srcSorted,
                                                     dinv, b1, W2, h2b);
    k_gather2_mean<<<N_NODES / 8, 256, 0, stream>>>(h2b, rowStart, srcSorted,
                                                    dinv, b2, g);
    k_out<<<1, 64, 0, stream>>>(g, Wfc, bfc, out);
}

// Round 7
// 136.722 us; speedup vs baseline: 2.2679x; 1.0860x over previous
//
#include <hip/hip_runtime.h>
#include <hip/hip_bf16.h>

#define N_NODES 10000
#define N_EDGES 640000
#define F_IN 128
#define H1 64
#define H2 32
#define N_CLASSES 16

#define NB 128        // radix buckets
#define NPB 79        // nodes per bucket (79*128 = 10112 >= 10000)
#define STAGE_C 64    // per-bucket LDS staging capacity (mean 16/blk)
#define SLOT 6144     // per-bucket partBuf capacity (mean ~5056)

// bf16 pair unpack: element j0 = low 16 bits (little-endian), j0+1 = high
__device__ __forceinline__ float bf_lo(unsigned u) {
    u <<= 16; float f; __builtin_memcpy(&f, &u, 4); return f;
}
__device__ __forceinline__ float bf_hi(unsigned u) {
    u &= 0xffff0000u; float f; __builtin_memcpy(&f, &u, 4); return f;
}

// ---------- pass 1: partition edges into 128 dst-range buckets ----------
// pack: src (14 bits, <10000) | local_dst (7 bits, <79) << 14
__global__ void __launch_bounds__(256) k_part(const int* __restrict__ src,
                                              const int* __restrict__ dst,
                                              int* __restrict__ bucketCursor,
                                              int* __restrict__ partBuf) {
    __shared__ int cnt[NB];
    __shared__ int gbase[NB];
    __shared__ int stage[NB * STAGE_C];
    int t = threadIdx.x;
    if (t < NB) cnt[t] = 0;
    __syncthreads();
    const int4* src4 = (const int4*)src;
    const int4* dst4 = (const int4*)dst;
#pragma unroll
    for (int k = 0; k < 2; ++k) {
        int i4 = blockIdx.x * 512 + k * 256 + t;
        if (i4 < N_EDGES / 4) {
            int4 s = src4[i4];
            int4 d = dst4[i4];
            int b, l, p;
            b = d.x / NPB; l = d.x - b * NPB; p = atomicAdd(&cnt[b], 1); stage[b * STAGE_C + p] = s.x | (l << 14);
            b = d.y / NPB; l = d.y - b * NPB; p = atomicAdd(&cnt[b], 1); stage[b * STAGE_C + p] = s.y | (l << 14);
            b = d.z / NPB; l = d.z - b * NPB; p = atomicAdd(&cnt[b], 1); stage[b * STAGE_C + p] = s.z | (l << 14);
            b = d.w / NPB; l = d.w - b * NPB; p = atomicAdd(&cnt[b], 1); stage[b * STAGE_C + p] = s.w | (l << 14);
        }
    }
    __syncthreads();
    if (t < NB) gbase[t] = atomicAdd(&bucketCursor[t], cnt[t]);
    __syncthreads();
    for (int i = t; i < NB * STAGE_C; i += 256) {
        int b = i >> 6;            // / STAGE_C
        int k = i & (STAGE_C - 1);
        if (k < cnt[b]) partBuf[b * SLOT + gbase[b] + k] = stage[i];
    }
}

// ---------- pass 2: per-bucket counting sort -> srcSorted, rowStart, dinv ----------
__global__ void __launch_bounds__(512) k_bsort(const int* __restrict__ bucketCursor,
                                               const int* __restrict__ partBuf,
                                               int* __restrict__ srcSorted,
                                               int* __restrict__ rowStart,
                                               float* __restrict__ dinv) {
    __shared__ int sc[NB];
    __shared__ int ldeg[NPB];
    __shared__ int lpre[NPB];
    __shared__ int cur[NPB];
    int t = threadIdx.x;
    int b = blockIdx.x;
    if (b == 0 && t == 0) rowStart[N_NODES] = N_EDGES;
    // redundant per-block scan of all 128 bucket totals
    if (t < NB) sc[t] = bucketCursor[t];
    __syncthreads();
    for (int off = 1; off < NB; off <<= 1) {
        int v = (t >= off && t < NB) ? sc[t - off] : 0;
        __syncthreads();
        if (t < NB) sc[t] += v;
        __syncthreads();
    }
    int cnt = bucketCursor[b];
    int base = sc[b] - cnt;  // exclusive prefix
    int nodeBase = b * NPB;
    int nNodes = N_NODES - nodeBase;
    if (nNodes <= 0) return;  // bucket 127 is empty
    if (nNodes > NPB) nNodes = NPB;
    if (t < NPB) ldeg[t] = 0;
    __syncthreads();
    // count local degrees
    for (int i = t; i < cnt; i += 512) {
        int p = partBuf[b * SLOT + i];
        atomicAdd(&ldeg[p >> 14], 1);
    }
    __syncthreads();
    if (t == 0) {
        int run = 0;
        for (int i = 0; i < nNodes; ++i) { lpre[i] = run; run += ldeg[i]; }
    }
    __syncthreads();
    if (t < nNodes) {
        int v = nodeBase + t;
        rowStart[v] = base + lpre[t];
        cur[t] = lpre[t];
        dinv[v] = rsqrtf((float)ldeg[t] + 1.0f);
    }
    __syncthreads();
    // place
    for (int i = t; i < cnt; i += 512) {
        int p = partBuf[b * SLOT + i];
        int pos = atomicAdd(&cur[p >> 14], 1);
        srcSorted[base + pos] = p & 16383;
    }
}

// ---------- layer1 GEMM: h1b = bf16((x @ W1) * dinv) ----------
// 625 blocks x 256 threads; 16 nodes/block; W1 (32KB) + x tile (8KB) in LDS.
__global__ void __launch_bounds__(256) k_gemm1(const float* __restrict__ x,
                                               const float* __restrict__ W1,
                                               const float* __restrict__ dinv,
                                               __hip_bfloat16* __restrict__ h1b) {
    __shared__ __align__(16) float w1s[F_IN][H1];  // 32 KB
    __shared__ __align__(16) float xs[16][F_IN];   // 8 KB
    int t = threadIdx.x;
    int node0 = blockIdx.x * 16;  // 625*16 = 10000 exact
    const float4* W14 = (const float4*)W1;
    float4* w1s4 = (float4*)w1s;
#pragma unroll
    for (int i = 0; i < 8; ++i) w1s4[i * 256 + t] = W14[i * 256 + t];
    const float4* x4 = (const float4*)(x + (long)node0 * F_IN);
    float4* xs4 = (float4*)xs;
#pragma unroll
    for (int i = 0; i < 2; ++i) xs4[i * 256 + t] = x4[i * 256 + t];
    __syncthreads();
    int j = t & 63;
    int q = t >> 6;       // wave id 0..3
    int r0 = q * 4;
    float acc0 = 0.f, acc1 = 0.f, acc2 = 0.f, acc3 = 0.f;
#pragma unroll 4
    for (int k = 0; k < F_IN; ++k) {
        float w = w1s[k][j];
        acc0 += xs[r0 + 0][k] * w;
        acc1 += xs[r0 + 1][k] * w;
        acc2 += xs[r0 + 2][k] * w;
        acc3 += xs[r0 + 3][k] * w;
    }
    int v0 = node0 + r0;
    h1b[(v0 + 0) * H1 + j] = __float2bfloat16(acc0 * dinv[v0 + 0]);
    h1b[(v0 + 1) * H1 + j] = __float2bfloat16(acc1 * dinv[v0 + 1]);
    h1b[(v0 + 2) * H1 + j] = __float2bfloat16(acc2 * dinv[v0 + 2]);
    h1b[(v0 + 3) * H1 + j] = __float2bfloat16(acc3 * dinv[v0 + 3]);
}

// ---------- gather layer1 (CSR, bf16x2) + ReLU + GEMM2 + dinv-scale ----------
// 1250 blocks x 256 threads = 8 nodes x 32 lanes; each lane owns feature pair
// (2*fp, 2*fp+1) as one uint load. Wave = 2 nodes -> 1 VMEM instr per 2 edges.
__global__ void __launch_bounds__(256) k_gather1_gemm2(const __hip_bfloat16* __restrict__ h1b,
                                const int* __restrict__ rowStart,
                                const int* __restrict__ srcSorted,
                                const float* __restrict__ dinv,
                                const float* __restrict__ b1,
                                const float* __restrict__ W2,
                                __hip_bfloat16* __restrict__ h2b) {
    __shared__ float h1s[8][H1];
    int t = threadIdx.x;
    int n  = t >> 5;        // node slot 0..7
    int fp = t & 31;        // feature pair
    int j0 = fp * 2;
    int v = blockIdx.x * 8 + n;   // 1250*8 = 10000 exact
    float dv_ = dinv[v];
    int rs = rowStart[v], re = rowStart[v + 1];
    const unsigned* h1u = (const unsigned*)h1b;
    unsigned su = h1u[v * 32 + fp];          // self-loop term
    float fx = bf_lo(su), fy = bf_hi(su);
    float x0 = 0.f, y0 = 0.f, x1 = 0.f, y1 = 0.f;
    float x2 = 0.f, y2 = 0.f, x3 = 0.f, y3 = 0.f;
    int e = rs;
    for (; e + 4 <= re; e += 4) {
        int i0 = srcSorted[e],     i1 = srcSorted[e + 1];
        int i2 = srcSorted[e + 2], i3 = srcSorted[e + 3];
        unsigned u0 = h1u[i0 * 32 + fp];
        unsigned u1 = h1u[i1 * 32 + fp];
        unsigned u2 = h1u[i2 * 32 + fp];
        unsigned u3 = h1u[i3 * 32 + fp];
        x0 += bf_lo(u0); y0 += bf_hi(u0);
        x1 += bf_lo(u1); y1 += bf_hi(u1);
        x2 += bf_lo(u2); y2 += bf_hi(u2);
        x3 += bf_lo(u3); y3 += bf_hi(u3);
    }
    for (; e < re; ++e) {
        unsigned u = h1u[srcSorted[e] * 32 + fp];
        fx += bf_lo(u); fy += bf_hi(u);
    }
    fx += (x0 + x1) + (x2 + x3);
    fy += (y0 + y1) + (y2 + y3);
    h1s[n][j0]     = fmaxf(dv_ * fx + b1[j0], 0.f);
    h1s[n][j0 + 1] = fmaxf(dv_ * fy + b1[j0 + 1], 0.f);
    __syncthreads();
    // GEMM2: thread = (node n, output j=fp in [0,32))
    float acc = 0.f;
#pragma unroll
    for (int kk = 0; kk < H1; ++kk)
        acc += h1s[n][kk] * W2[kk * H2 + fp];
    h2b[v * H2 + fp] = __float2bfloat16(acc * dv_);  // pre-scaled
}

// ---------- gather layer2 (CSR, bf16x2) + ReLU + block mean reduce ----------
// 625 blocks x 256 threads = 16 nodes x 16 lanes; wave = 4 nodes.
__global__ void __launch_bounds__(256) k_gather2_mean(const __hip_bfloat16* __restrict__ h2b,
                               const int* __restrict__ rowStart,
                               const int* __restrict__ srcSorted,
                               const float* __restrict__ dinv,
                               const float* __restrict__ b2,
                               float* __restrict__ g) {
    __shared__ float red[16][H2];
    int t = threadIdx.x;
    int n  = t >> 4;        // node slot 0..15
    int fp = t & 15;        // feature pair of H2
    int j0 = fp * 2;
    int v = blockIdx.x * 16 + n;   // 625*16 = 10000 exact
    float dv_ = dinv[v];
    int rs = rowStart[v], re = rowStart[v + 1];
    const unsigned* h2u = (const unsigned*)h2b;
    unsigned su = h2u[v * 16 + fp];          // self-loop term
    float fx = bf_lo(su), fy = bf_hi(su);
    float x0 = 0.f, y0 = 0.f, x1 = 0.f, y1 = 0.f;
    float x2 = 0.f, y2 = 0.f, x3 = 0.f, y3 = 0.f;
    int e = rs;
    for (; e + 4 <= re; e += 4) {
        int i0 = srcSorted[e],     i1 = srcSorted[e + 1];
        int i2 = srcSorted[e + 2], i3 = srcSorted[e + 3];
        unsigned u0 = h2u[i0 * 16 + fp];
        unsigned u1 = h2u[i1 * 16 + fp];
        unsigned u2 = h2u[i2 * 16 + fp];
        unsigned u3 = h2u[i3 * 16 + fp];
        x0 += bf_lo(u0); y0 += bf_hi(u0);
        x1 += bf_lo(u1); y1 += bf_hi(u1);
        x2 += bf_lo(u2); y2 += bf_hi(u2);
        x3 += bf_lo(u3); y3 += bf_hi(u3);
    }
    for (; e < re; ++e) {
        unsigned u = h2u[srcSorted[e] * 16 + fp];
        fx += bf_lo(u); fy += bf_hi(u);
    }
    fx += (x0 + x1) + (x2 + x3);
    fy += (y0 + y1) + (y2 + y3);
    red[n][j0]     = fmaxf(dv_ * fx + b2[j0], 0.f);
    red[n][j0 + 1] = fmaxf(dv_ * fy + b2[j0 + 1], 0.f);
    __syncthreads();
    if (t < 32) {
        float s = 0.f;
#pragma unroll
        for (int r = 0; r < 16; ++r) s += red[r][t];
        atomicAdd(&g[t], s);
    }
}

// ---------- final FC ----------
__global__ void k_out(const float* __restrict__ g,
                      const float* __restrict__ Wfc,
                      const float* __restrict__ bfc,
                      float* __restrict__ out) {
    int c = threadIdx.x;
    if (c < N_CLASSES) {
        float acc = 0.f;
#pragma unroll
        for (int j = 0; j < H2; ++j)
            acc += g[j] * Wfc[j * N_CLASSES + c];
        float invN = 1.0f / (float)N_NODES;
        out[c] = acc * invN + bfc[c];
    }
}

extern "C" void kernel_launch(void* const* d_in, const int* in_sizes, int n_in,
                              void* d_out, int out_size, void* d_ws, size_t ws_size,
                              hipStream_t stream) {
    const float* x   = (const float*)d_in[0];
    const float* W1  = (const float*)d_in[1];
    const float* b1  = (const float*)d_in[2];
    const float* W2  = (const float*)d_in[3];
    const float* b2  = (const float*)d_in[4];
    const float* Wfc = (const float*)d_in[5];
    const float* bfc = (const float*)d_in[6];
    const int* edge = (const int*)d_in[7];
    const int* srcI = edge;              // edge_index[0]
    const int* dstI = edge + N_EDGES;    // edge_index[1]
    float* out = (float*)d_out;

    // workspace layout. partBuf is dead after k_bsort; h1b/h2b overlay it
    // (first written by k_gemm1 / k_gather1_gemm2, stream-order serialized).
    char* ws = (char*)d_ws;
    int*   bucketCursor = (int*)  (ws + 0);        // 128 ints
    float* g            = (float*)(ws + 512);      // 32 f
    float* dinv         = (float*)(ws + 1024);     // 10000 f
    int*   rowStart     = (int*)  (ws + 41984);    // 10001 ints
    int*   srcSorted    = (int*)  (ws + 82944);    // 640000 ints -> ends 2642944
    int*   partBuf      = (int*)  (ws + 2643968);  // 128*6144 ints -> ends 5789696
    __hip_bfloat16* h1b = (__hip_bfloat16*)(ws + 2643968);  // 640000 bf16 (overlays partBuf)
    __hip_bfloat16* h2b = (__hip_bfloat16*)(ws + 3923968);  // 320000 bf16 (overlays partBuf)

    hipMemsetAsync(bucketCursor, 0, 640, stream);  // bucketCursor + g

    k_part<<<(N_EDGES / 4 + 511) / 512, 256, 0, stream>>>(srcI, dstI, bucketCursor, partBuf);
    k_bsort<<<NB, 512, 0, stream>>>(bucketCursor, partBuf, srcSorted, rowStart, dinv);
    k_gemm1<<<N_NODES / 16, 256, 0, stream>>>(x, W1, dinv, h1b);
    k_gather1_gemm2<<<N_NODES / 8, 256, 0, stream>>>(h1b, rowStart, srcSorted,
                                                     dinv, b1, W2, h2b);
    k_gather2_mean<<<N_NODES / 16, 256, 0, stream>>>(h2b, rowStart, srcSorted,
                                                     dinv, b2, g);
    k_out<<<1, 64, 0, stream>>>(g, Wfc, bfc, out);
}